// Round 1
// baseline (600.632 us; speedup 1.0000x reference)
//
#include <hip/hip_runtime.h>

#define BATCH 2048
#define HID 1024
#define FFN 4096
#define NEXP 8
#define MAXROWS 5120   // sum ceil(count_e/128)*128 <= 4096 + 8*127 -> round up
#define MTILES 40      // MAXROWS/128

typedef __attribute__((ext_vector_type(8))) short short8;
typedef __attribute__((ext_vector_type(4))) float floatx4;

// fp32 -> bf16 round-to-nearest-even
static __device__ inline unsigned short f2bf(float f) {
    unsigned int u = __float_as_uint(f);
    unsigned int r = (u + 0x7fffu + ((u >> 16) & 1u)) >> 16;
    return (unsigned short)r;
}

static __device__ inline int load_idx(const int* idx32, int flat, int is32) {
    return is32 ? idx32[flat] : idx32[2 * flat];  // int64 little-endian low word
}

// async global -> LDS, 16B per lane. LDS dest must be wave-uniform base; HW
// writes base + lane*16 (m97 pattern). Global src is per-lane.
static __device__ inline void gload_lds16(const unsigned short* g, unsigned short* l) {
    __builtin_amdgcn_global_load_lds(
        (const __attribute__((address_space(1))) unsigned int*)g,
        (__attribute__((address_space(3))) unsigned int*)l,
        16, 0, 0);
}

// fused: detect int32/int64 layout, per-expert counts, padded prefix sum.
// Single block => __syncthreads gives the needed global ordering.
__global__ void route_all(const int* __restrict__ idx32, int* __restrict__ fmt,
                          int* __restrict__ counts, int* __restrict__ pbase,
                          int* __restrict__ cursor) {
    __shared__ int s_cnt[NEXP];
    __shared__ int s_fmt;
    int t = threadIdx.x;  // 1024 threads
    if (t < NEXP) s_cnt[t] = 0;
    if (t == 0) s_fmt = 0;
    __syncthreads();
    int bad = 0;
    for (int i = t; i < BATCH; i += 1024)       // odd words of first BATCH values
        if (idx32[2 * i + 1] != 0) bad = 1;     // in-bounds for both layouts
    if (bad) atomicOr(&s_fmt, 1);               // nonzero odd word -> plain int32
    __syncthreads();
    int is32 = s_fmt;
    for (int b = t; b < BATCH; b += 1024) {
        int e0 = load_idx(idx32, 2 * b, is32);
        int e1 = load_idx(idx32, 2 * b + 1, is32);
        atomicAdd(&s_cnt[e0], 1);
        if (e1 != e0) atomicAdd(&s_cnt[e1], 1);
    }
    __syncthreads();
    if (t == 0) {
        fmt[0] = is32;
        int acc = 0;
        for (int e = 0; e < NEXP; e++) {
            counts[e] = s_cnt[e];
            pbase[e] = acc;
            cursor[e] = acc;
            acc += ((s_cnt[e] + 127) >> 7) << 7;
        }
        pbase[NEXP] = acc;
    }
}

__global__ void scatter_gather(const float* __restrict__ x, const float* __restrict__ rw,
                               const int* __restrict__ idx32, const int* __restrict__ fmt,
                               int* __restrict__ cursor, int* __restrict__ tids,
                               float* __restrict__ twt, unsigned short* __restrict__ Apk) {
    __shared__ int s_slot[2];
    __shared__ int s_n;
    int b = blockIdx.x;
    if (threadIdx.x == 0) {
        int is32 = fmt[0];
        int e0 = load_idx(idx32, 2 * b, is32);
        int e1 = load_idx(idx32, 2 * b + 1, is32);
        float w0 = rw[2 * b], w1 = rw[2 * b + 1];
        int n, ee[2];
        float ww[2];
        if (e0 == e1) { n = 1; ee[0] = e0; ww[0] = w0 + w1; }
        else { n = 2; ee[0] = e0; ww[0] = w0; ee[1] = e1; ww[1] = w1; }
        for (int j = 0; j < n; j++) {
            int slot = atomicAdd(&cursor[ee[j]], 1);
            s_slot[j] = slot;
            tids[slot] = b;
            twt[slot] = ww[j];
        }
        s_n = n;
    }
    __syncthreads();
    int n = s_n;
    const float4* src = (const float4*)(x + (size_t)b * HID);
    for (int j = 0; j < n; j++) {
        unsigned short* dst = Apk + (size_t)s_slot[j] * HID;
        #pragma unroll
        for (int r = 0; r < 2; r++) {
            int i = threadIdx.x + r * 128;
            float4 v = src[i];
            union { unsigned short u[4]; uint2 q; } p;
            p.u[0] = f2bf(v.x); p.u[1] = f2bf(v.y);
            p.u[2] = f2bf(v.z); p.u[3] = f2bf(v.w);
            *(uint2*)(dst + i * 4) = p.q;
        }
    }
}

// convert fp32 W[E][K][N] -> bf16 Wt[E][N][K] (transpose via 64x64 LDS tile)
__global__ void conv_transpose(const float* __restrict__ W, unsigned short* __restrict__ Wt,
                               int K, int N) {
    __shared__ unsigned short sT[64][65];
    int e = blockIdx.z;
    int kt = blockIdx.y * 64, nt = blockIdx.x * 64;
    const float* src = W + ((size_t)e * K + kt) * N + nt;
    #pragma unroll
    for (int i = 0; i < 4; i++) {
        int t = threadIdx.x + i * 256;          // 0..1023, 64 rows x 16 float4
        int r = t >> 4, c4 = (t & 15) * 4;
        float4 v = *(const float4*)(src + (size_t)r * N + c4);
        sT[c4 + 0][r] = f2bf(v.x);
        sT[c4 + 1][r] = f2bf(v.y);
        sT[c4 + 2][r] = f2bf(v.z);
        sT[c4 + 3][r] = f2bf(v.w);
    }
    __syncthreads();
    #pragma unroll
    for (int i = 0; i < 2; i++) {
        int u = threadIdx.x + i * 256;          // 0..511, 64 rows x 8 uint4
        int n = u >> 3, k8 = (u & 7) * 8;
        union { unsigned short h[8]; uint4 q; } p;
        #pragma unroll
        for (int j = 0; j < 8; j++) p.h[j] = sT[n][k8 + j];
        *(uint4*)(Wt + ((size_t)e * N + nt + n) * K + kt + k8) = p.q;
    }
}

// m97-structure GEMM: 128x128 tile, BK=32, double-buffered LDS staged via
// global_load_lds width=16 (direct-to-LDS DMA, no VGPR round trip), one
// __syncthreads per k-iter. A: bf16 [rows][KTOT], Bt: bf16 [E][NTOT][KTOT].
// NFAST selects swizzle decode: 0 = m-fastest (cluster same-(expert,ncol)
// B-panel sharers per XCD), 1 = n-fastest (cluster same-m A-slice sharers).
template <int KTOT, int NTOT, bool SILU, int KSPLIT, int NFAST>
__global__ __launch_bounds__(256, 4) void gemm_lds(
    const unsigned short* __restrict__ Abuf, const unsigned short* __restrict__ Bt,
    unsigned short* __restrict__ Hout, float* __restrict__ Out,
    const int* __restrict__ tids, const float* __restrict__ twt,
    const int* __restrict__ counts, const int* __restrict__ pbase) {
    __shared__ __align__(16) unsigned short sA[2][128 * 32];
    __shared__ __align__(16) unsigned short sB[2][128 * 32];

    // bijective XCD swizzle (nwg % 8 == 0 for all grids used here)
    int gx = gridDim.x, gy = gridDim.y;
    int nwg = gx * gy;
    int flat = blockIdx.y * gx + blockIdx.x;
    int q = nwg >> 3;
    int sw = (flat & 7) * q + (flat >> 3);
    int bm, bn;
    if (NFAST) { bn = sw % gy; bm = sw / gy; }
    else       { bm = sw % gx; bn = sw / gx; }

    int row0 = bm * 128;
    if (row0 >= pbase[NEXP]) return;
    int e = 0;
    while (row0 >= pbase[e + 1]) e++;
    int n0 = bn * 128;
    constexpr int KCH = KTOT / KSPLIT;
    constexpr int NK = KCH / 32;
    int kb = blockIdx.z * KCH;

    const unsigned short* Aw = Abuf + (size_t)row0 * KTOT + kb;
    const unsigned short* Bw = Bt + ((size_t)e * NTOT + n0) * KTOT + kb;

    int tid = threadIdx.x;
    int lane = tid & 63, wid = tid >> 6;
    int wm = wid & 1, wn = wid >> 1;
    int quad = lane >> 4, l16 = lane & 15;

    // staging: 512 16B-chunks per 128x32 tile (4 chunks/row); wave w owns
    // chunks [w*128, w*128+128) via two global_load_lds (64 lanes x 16B each).
    int c0 = wid * 128 + lane;
    int c1 = c0 + 64;
    const unsigned short* gA0 = Aw + (size_t)(c0 >> 2) * KTOT + (c0 & 3) * 8;
    const unsigned short* gA1 = Aw + (size_t)(c1 >> 2) * KTOT + (c1 & 3) * 8;
    const unsigned short* gB0 = Bw + (size_t)(c0 >> 2) * KTOT + (c0 & 3) * 8;
    const unsigned short* gB1 = Bw + (size_t)(c1 >> 2) * KTOT + (c1 & 3) * 8;
    const int d0 = wid * 1024;   // shorts: wave base chunk * 8
    const int d1 = d0 + 512;

    floatx4 acc[4][4];
    #pragma unroll
    for (int i = 0; i < 4; i++)
        #pragma unroll
        for (int j = 0; j < 4; j++) acc[i][j] = (floatx4)0.f;

    // prologue: stage k-tile 0
    gload_lds16(gA0, &sA[0][d0]);
    gload_lds16(gA1, &sA[0][d1]);
    gload_lds16(gB0, &sB[0][d0]);
    gload_lds16(gB1, &sB[0][d1]);
    __syncthreads();   // implies vmcnt(0): tile 0 resident

    for (int k = 0;; k++) {
        int cur = k & 1;
        if (k + 1 < NK) {
            // issue next-tile DMA first so its latency hides under ds_read+MFMA
            int off = (k + 1) * 32;
            int nxt = cur ^ 1;
            gload_lds16(gA0 + off, &sA[nxt][d0]);
            gload_lds16(gA1 + off, &sA[nxt][d1]);
            gload_lds16(gB0 + off, &sB[nxt][d0]);
            gload_lds16(gB1 + off, &sB[nxt][d1]);
        }
        short8 af[4], bfv[4];
        #pragma unroll
        for (int mi = 0; mi < 4; mi++)
            af[mi] = *(const short8*)(sA[cur] + (wm * 64 + mi * 16 + l16) * 32 + quad * 8);
        #pragma unroll
        for (int ni = 0; ni < 4; ni++)
            bfv[ni] = *(const short8*)(sB[cur] + (wn * 64 + ni * 16 + l16) * 32 + quad * 8);
        #pragma unroll
        for (int mi = 0; mi < 4; mi++)
            #pragma unroll
            for (int ni = 0; ni < 4; ni++)
                acc[mi][ni] = __builtin_amdgcn_mfma_f32_16x16x32_bf16(af[mi], bfv[ni], acc[mi][ni], 0, 0, 0);
        if (k + 1 >= NK) break;
        __syncthreads();   // drains vmcnt(0): next tile resident; orders reads-before-overwrite
    }

    int cnt = counts[e], pb = pbase[e];
    #pragma unroll
    for (int mi = 0; mi < 4; mi++) {
        int rbase = row0 + wm * 64 + mi * 16 + quad * 4;
        #pragma unroll
        for (int ni = 0; ni < 4; ni++) {
            int col = n0 + wn * 64 + ni * 16 + l16;
            #pragma unroll
            for (int r = 0; r < 4; r++) {
                float v = acc[mi][ni][r];
                int row = rbase + r;
                if (SILU) {
                    float s = v / (1.f + __expf(-v));
                    Hout[(size_t)row * NTOT + col] = f2bf(s);
                } else {
                    if (row - pb < cnt) {
                        int t = tids[row];
                        if (t >= 0 && t < BATCH)
                            atomicAdd(&Out[(size_t)t * HID + col], v * twt[row]);
                    }
                }
            }
        }
    }
}

// ---------- fallback (fused-convert GEMM, proven) if ws too small ----------
template <int KTOT, int NTOT, bool SILU>
__global__ __launch_bounds__(256, 2) void gemm_fused(
    const unsigned short* __restrict__ Abuf, const float* __restrict__ Wall,
    unsigned short* __restrict__ Hout, float* __restrict__ Out,
    const int* __restrict__ tids, const float* __restrict__ twt,
    const int* __restrict__ counts, const int* __restrict__ pbase) {
    __shared__ __align__(16) unsigned short sA[128][40];
    __shared__ __align__(16) unsigned short sB[128][40];
    int row0 = blockIdx.x * 128;
    if (row0 >= pbase[NEXP]) return;
    int e = 0;
    while (row0 >= pbase[e + 1]) e++;
    int n0 = blockIdx.y * 128;
    const float* Bw = Wall + (size_t)e * KTOT * NTOT;
    int tid = threadIdx.x;
    int lane = tid & 63, wid = tid >> 6;
    int wm = wid & 1, wn = wid >> 1;
    int quad = lane >> 4, l16 = lane & 15;
    floatx4 acc[4][4];
    #pragma unroll
    for (int i = 0; i < 4; i++)
        #pragma unroll
        for (int j = 0; j < 4; j++) acc[i][j] = (floatx4)0.f;
    for (int k0 = 0; k0 < KTOT; k0 += 32) {
        #pragma unroll
        for (int i = 0; i < 2; i++) {
            int q2 = tid + i * 256;
            int r = q2 >> 2, c8 = (q2 & 3) * 8;
            uint4 v = *(const uint4*)(Abuf + (size_t)(row0 + r) * KTOT + k0 + c8);
            *(uint4*)(&sA[r][c8]) = v;
        }
        {
            int k = tid >> 3, n16 = (tid & 7) * 16;
            const float* bp = Bw + (size_t)(k0 + k) * NTOT + n0 + n16;
            #pragma unroll
            for (int j = 0; j < 4; j++) {
                float4 v = *(const float4*)(bp + j * 4);
                sB[n16 + j * 4 + 0][k] = f2bf(v.x);
                sB[n16 + j * 4 + 1][k] = f2bf(v.y);
                sB[n16 + j * 4 + 2][k] = f2bf(v.z);
                sB[n16 + j * 4 + 3][k] = f2bf(v.w);
            }
        }
        __syncthreads();
        short8 af[4], bfr[4];
        #pragma unroll
        for (int mi = 0; mi < 4; mi++)
            af[mi] = *(const short8*)(&sA[wm * 64 + mi * 16 + l16][quad * 8]);
        #pragma unroll
        for (int ni = 0; ni < 4; ni++)
            bfr[ni] = *(const short8*)(&sB[wn * 64 + ni * 16 + l16][quad * 8]);
        #pragma unroll
        for (int mi = 0; mi < 4; mi++)
            #pragma unroll
            for (int ni = 0; ni < 4; ni++)
                acc[mi][ni] = __builtin_amdgcn_mfma_f32_16x16x32_bf16(af[mi], bfr[ni], acc[mi][ni], 0, 0, 0);
        __syncthreads();
    }
    int cnt = counts[e], pb = pbase[e];
    #pragma unroll
    for (int mi = 0; mi < 4; mi++) {
        int rbase = row0 + wm * 64 + mi * 16 + quad * 4;
        #pragma unroll
        for (int ni = 0; ni < 4; ni++) {
            int col = n0 + wn * 64 + ni * 16 + l16;
            #pragma unroll
            for (int r = 0; r < 4; r++) {
                float v = acc[mi][ni][r];
                int row = rbase + r;
                if (SILU) {
                    float s = v / (1.f + __expf(-v));
                    Hout[(size_t)row * NTOT + col] = f2bf(s);
                } else {
                    if (row - pb < cnt) {
                        int t = tids[row];
                        if (t >= 0 && t < BATCH)
                            atomicAdd(&Out[(size_t)t * HID + col], v * twt[row]);
                    }
                }
            }
        }
    }
}

extern "C" void kernel_launch(void* const* d_in, const int* in_sizes, int n_in,
                              void* d_out, int out_size, void* d_ws, size_t ws_size,
                              hipStream_t stream) {
    const float* x = (const float*)d_in[0];
    const float* rw = (const float*)d_in[1];
    const float* w1 = (const float*)d_in[2];
    const float* w2 = (const float*)d_in[3];
    const int* idx32 = (const int*)d_in[4];
    float* out = (float*)d_out;

    char* ws = (char*)d_ws;
    int* counts = (int*)(ws + 0);
    int* cursor = (int*)(ws + 64);
    int* pbase  = (int*)(ws + 128);
    int* fmt    = (int*)(ws + 192);
    int* tids   = (int*)(ws + 4096);
    float* twt  = (float*)(ws + 4096 + MAXROWS * 4);

    size_t off = 65536;
    unsigned short* Apk  = (unsigned short*)(ws + off);  off += (size_t)MAXROWS * HID * 2;    // 10.5 MB
    unsigned short* Hact = (unsigned short*)(ws + off);  off += (size_t)MAXROWS * FFN * 2;    // 41.9 MB
    unsigned short* w1t  = (unsigned short*)(ws + off);  off += (size_t)NEXP * HID * FFN * 2; // 67.1 MB
    unsigned short* w2t  = (unsigned short*)(ws + off);  off += (size_t)NEXP * FFN * HID * 2; // 67.1 MB
    const bool big = ws_size >= off;   // constant per session -> graph-safe branch

    // zero meta + tids/twt + Apk in one shot (padding rows become true zeros)
    hipMemsetAsync(d_ws, 0, 65536 + (size_t)MAXROWS * HID * 2, stream);
    hipMemsetAsync(d_out, 0, (size_t)out_size * sizeof(float), stream);

    route_all<<<1, 1024, 0, stream>>>(idx32, fmt, counts, pbase, cursor);
    scatter_gather<<<BATCH, 128, 0, stream>>>(x, rw, idx32, fmt, cursor, tids, twt, Apk);

    if (big) {
        conv_transpose<<<dim3(FFN / 64, HID / 64, NEXP), 256, 0, stream>>>(w1, w1t, HID, FFN);
        conv_transpose<<<dim3(HID / 64, FFN / 64, NEXP), 256, 0, stream>>>(w2, w2t, FFN, HID);
        gemm_lds<HID, FFN, true, 1, 0><<<dim3(MTILES, FFN / 128, 1), 256, 0, stream>>>(
            Apk, w1t, Hact, nullptr, tids, twt, counts, pbase);
        gemm_lds<FFN, HID, false, 4, 1><<<dim3(MTILES, HID / 128, 4), 256, 0, stream>>>(
            Hact, w2t, nullptr, out, tids, twt, counts, pbase);
    } else {
        gemm_fused<HID, FFN, true><<<dim3(MTILES, FFN / 128), 256, 0, stream>>>(
            Apk, w1, Hact, nullptr, tids, twt, counts, pbase);
        gemm_fused<FFN, HID, false><<<dim3(MTILES, HID / 128), 256, 0, stream>>>(
            Hact, w2, nullptr, out, tids, twt, counts, pbase);
    }
}

// Round 2
// 581.699 us; speedup vs baseline: 1.0325x; 1.0325x over previous
//
#include <hip/hip_runtime.h>

#define BATCH 2048
#define HID 1024
#define FFN 4096
#define NEXP 8
#define MAXROWS 5120   // sum ceil(count_e/128)*128 <= 4096 + 8*127 -> round up
#define MTILES 40      // MAXROWS/128

typedef __attribute__((ext_vector_type(8))) short short8;
typedef __attribute__((ext_vector_type(4))) float floatx4;

// fp32 -> bf16 round-to-nearest-even
static __device__ inline unsigned short f2bf(float f) {
    unsigned int u = __float_as_uint(f);
    unsigned int r = (u + 0x7fffu + ((u >> 16) & 1u)) >> 16;
    return (unsigned short)r;
}

static __device__ inline int load_idx(const int* idx32, int flat, int is32) {
    return is32 ? idx32[flat] : idx32[2 * flat];  // int64 little-endian low word
}

// fused: detect int32/int64 layout, per-expert counts, padded prefix sum.
// Single block => __syncthreads gives the needed global ordering.
__global__ void route_all(const int* __restrict__ idx32, int* __restrict__ fmt,
                          int* __restrict__ counts, int* __restrict__ pbase,
                          int* __restrict__ cursor) {
    __shared__ int s_cnt[NEXP];
    __shared__ int s_fmt;
    int t = threadIdx.x;  // 1024 threads
    if (t < NEXP) s_cnt[t] = 0;
    if (t == 0) s_fmt = 0;
    __syncthreads();
    int bad = 0;
    for (int i = t; i < BATCH; i += 1024)       // odd words of first BATCH values
        if (idx32[2 * i + 1] != 0) bad = 1;     // in-bounds for both layouts
    if (bad) atomicOr(&s_fmt, 1);               // nonzero odd word -> plain int32
    __syncthreads();
    int is32 = s_fmt;
    for (int b = t; b < BATCH; b += 1024) {
        int e0 = load_idx(idx32, 2 * b, is32);
        int e1 = load_idx(idx32, 2 * b + 1, is32);
        atomicAdd(&s_cnt[e0], 1);
        if (e1 != e0) atomicAdd(&s_cnt[e1], 1);
    }
    __syncthreads();
    if (t == 0) {
        fmt[0] = is32;
        int acc = 0;
        for (int e = 0; e < NEXP; e++) {
            counts[e] = s_cnt[e];
            pbase[e] = acc;
            cursor[e] = acc;
            acc += ((s_cnt[e] + 127) >> 7) << 7;
        }
        pbase[NEXP] = acc;
    }
}

__global__ void scatter_gather(const float* __restrict__ x, const float* __restrict__ rw,
                               const int* __restrict__ idx32, const int* __restrict__ fmt,
                               int* __restrict__ cursor, int* __restrict__ tids,
                               float* __restrict__ twt, unsigned short* __restrict__ Apk) {
    __shared__ int s_slot[2];
    __shared__ int s_n;
    int b = blockIdx.x;
    if (threadIdx.x == 0) {
        int is32 = fmt[0];
        int e0 = load_idx(idx32, 2 * b, is32);
        int e1 = load_idx(idx32, 2 * b + 1, is32);
        float w0 = rw[2 * b], w1 = rw[2 * b + 1];
        int n, ee[2];
        float ww[2];
        if (e0 == e1) { n = 1; ee[0] = e0; ww[0] = w0 + w1; }
        else { n = 2; ee[0] = e0; ww[0] = w0; ee[1] = e1; ww[1] = w1; }
        for (int j = 0; j < n; j++) {
            int slot = atomicAdd(&cursor[ee[j]], 1);
            s_slot[j] = slot;
            tids[slot] = b;
            twt[slot] = ww[j];
        }
        s_n = n;
    }
    __syncthreads();
    int n = s_n;
    const float4* src = (const float4*)(x + (size_t)b * HID);
    for (int j = 0; j < n; j++) {
        unsigned short* dst = Apk + (size_t)s_slot[j] * HID;
        #pragma unroll
        for (int r = 0; r < 2; r++) {
            int i = threadIdx.x + r * 128;
            float4 v = src[i];
            union { unsigned short u[4]; uint2 q; } p;
            p.u[0] = f2bf(v.x); p.u[1] = f2bf(v.y);
            p.u[2] = f2bf(v.z); p.u[3] = f2bf(v.w);
            *(uint2*)(dst + i * 4) = p.q;
        }
    }
}

// convert fp32 W[E][K][N] -> bf16 Wt[E][N][K] (transpose via 64x64 LDS tile)
__global__ void conv_transpose(const float* __restrict__ W, unsigned short* __restrict__ Wt,
                               int K, int N) {
    __shared__ unsigned short sT[64][65];
    int e = blockIdx.z;
    int kt = blockIdx.y * 64, nt = blockIdx.x * 64;
    const float* src = W + ((size_t)e * K + kt) * N + nt;
    #pragma unroll
    for (int i = 0; i < 4; i++) {
        int t = threadIdx.x + i * 256;          // 0..1023, 64 rows x 16 float4
        int r = t >> 4, c4 = (t & 15) * 4;
        float4 v = *(const float4*)(src + (size_t)r * N + c4);
        sT[c4 + 0][r] = f2bf(v.x);
        sT[c4 + 1][r] = f2bf(v.y);
        sT[c4 + 2][r] = f2bf(v.z);
        sT[c4 + 3][r] = f2bf(v.w);
    }
    __syncthreads();
    #pragma unroll
    for (int i = 0; i < 2; i++) {
        int u = threadIdx.x + i * 256;          // 0..511, 64 rows x 8 uint4
        int n = u >> 3, k8 = (u & 7) * 8;
        union { unsigned short h[8]; uint4 q; } p;
        #pragma unroll
        for (int j = 0; j < 8; j++) p.h[j] = sT[n][k8 + j];
        *(uint4*)(Wt + ((size_t)e * N + nt + n) * K + kt + k8) = p.q;
    }
}

// Reg-staged double-buffered 128x128 tile, BK=32, register prefetch of next
// k-tile (compiler emits counted vmcnt waits -> loads stay in flight across
// the barrier), one barrier per iteration. LDS slot-swizzle: 16B slot index
// s within a row is stored at s ^ ((row>>1)&3). Writes keep the same bank
// pattern as linear (permutation within each 64B pair); fragment reads drop
// from 8-way to 2-way (free) bank aliasing.
// A: bf16 [rows][KTOT], Bt: bf16 [E][NTOT][KTOT].
// NFAST: swizzle decode; 0 = m-fastest per XCD, 1 = n-fastest per XCD.
template <int KTOT, int NTOT, bool SILU, int KSPLIT, int NFAST>
__global__ __launch_bounds__(256, 2) void gemm_db(
    const unsigned short* __restrict__ Abuf, const unsigned short* __restrict__ Bt,
    unsigned short* __restrict__ Hout, float* __restrict__ Out,
    const int* __restrict__ tids, const float* __restrict__ twt,
    const int* __restrict__ counts, const int* __restrict__ pbase) {
    __shared__ __align__(16) unsigned short sA[2][128 * 32];
    __shared__ __align__(16) unsigned short sB[2][128 * 32];

    // bijective XCD swizzle (nwg % 8 == 0 for all grids used here)
    int gx = gridDim.x, gy = gridDim.y;
    int nwg = gx * gy;
    int flat = blockIdx.y * gx + blockIdx.x;
    int q = nwg >> 3;
    int sw = (flat & 7) * q + (flat >> 3);
    int bm, bn;
    if (NFAST) { bn = sw % gy; bm = sw / gy; }
    else       { bm = sw % gx; bn = sw / gx; }

    int row0 = bm * 128;
    if (row0 >= pbase[NEXP]) return;
    int e = 0;
    while (row0 >= pbase[e + 1]) e++;
    int n0 = bn * 128;
    constexpr int KCH = KTOT / KSPLIT;
    constexpr int NK = KCH / 32;
    int kb = blockIdx.z * KCH;

    const unsigned short* Aw = Abuf + (size_t)row0 * KTOT + kb;
    const unsigned short* Bw = Bt + ((size_t)e * NTOT + n0) * KTOT + kb;

    int tid = threadIdx.x;
    int lane = tid & 63, wid = tid >> 6;
    int wm = wid & 1, wn = wid >> 1;
    int quad = lane >> 4, l16 = lane & 15;

    // staging: 512 16B-chunks per 128x32 tile; thread covers chunks tid and
    // tid+256 (rows r and r+64 -> same swizzle phase, dest +4096B).
    int r0 = tid >> 2, c8 = (tid & 3);
    const size_t aoff0 = (size_t)r0 * KTOT + c8 * 8;
    const size_t aoff1 = (size_t)(r0 + 64) * KTOT + c8 * 8;
    const int sl = c8 ^ ((r0 >> 1) & 3);
    const int ldso0 = r0 * 64 + sl * 16;       // bytes
    const int ldso1 = ldso0 + 4096;
    // fragment read slot (shorts): quad-th 16B of a row, swizzled by row phase
    const int sq = (quad ^ ((l16 >> 1) & 3)) * 8;

    floatx4 acc[4][4];
    #pragma unroll
    for (int i = 0; i < 4; i++)
        #pragma unroll
        for (int j = 0; j < 4; j++) acc[i][j] = (floatx4)0.f;

    uint4 va0 = *(const uint4*)(Aw + aoff0);
    uint4 va1 = *(const uint4*)(Aw + aoff1);
    uint4 vb0 = *(const uint4*)(Bw + aoff0);
    uint4 vb1 = *(const uint4*)(Bw + aoff1);
    *(uint4*)((char*)sA[0] + ldso0) = va0;
    *(uint4*)((char*)sA[0] + ldso1) = va1;
    *(uint4*)((char*)sB[0] + ldso0) = vb0;
    *(uint4*)((char*)sB[0] + ldso1) = vb1;
    __syncthreads();

    for (int k = 0;; k++) {
        int cur = k & 1;
        bool more = (k + 1 < NK);
        if (more) {
            const unsigned short* Ak = Aw + (k + 1) * 32;
            const unsigned short* Bk = Bw + (k + 1) * 32;
            va0 = *(const uint4*)(Ak + aoff0);
            va1 = *(const uint4*)(Ak + aoff1);
            vb0 = *(const uint4*)(Bk + aoff0);
            vb1 = *(const uint4*)(Bk + aoff1);
        }
        short8 af[4], bfv[4];
        #pragma unroll
        for (int mi = 0; mi < 4; mi++)
            af[mi] = *(const short8*)(sA[cur] + (wm * 64 + mi * 16 + l16) * 32 + sq);
        #pragma unroll
        for (int ni = 0; ni < 4; ni++)
            bfv[ni] = *(const short8*)(sB[cur] + (wn * 64 + ni * 16 + l16) * 32 + sq);
        #pragma unroll
        for (int mi = 0; mi < 4; mi++)
            #pragma unroll
            for (int ni = 0; ni < 4; ni++)
                acc[mi][ni] = __builtin_amdgcn_mfma_f32_16x16x32_bf16(af[mi], bfv[ni], acc[mi][ni], 0, 0, 0);
        if (!more) break;
        int nxt = cur ^ 1;
        *(uint4*)((char*)sA[nxt] + ldso0) = va0;
        *(uint4*)((char*)sA[nxt] + ldso1) = va1;
        *(uint4*)((char*)sB[nxt] + ldso0) = vb0;
        *(uint4*)((char*)sB[nxt] + ldso1) = vb1;
        __syncthreads();
    }

    int cnt = counts[e], pb = pbase[e];
    #pragma unroll
    for (int mi = 0; mi < 4; mi++) {
        int rbase = row0 + wm * 64 + mi * 16 + quad * 4;
        #pragma unroll
        for (int ni = 0; ni < 4; ni++) {
            int col = n0 + wn * 64 + ni * 16 + l16;
            #pragma unroll
            for (int r = 0; r < 4; r++) {
                float v = acc[mi][ni][r];
                int row = rbase + r;
                if (SILU) {
                    float s = v / (1.f + __expf(-v));
                    Hout[(size_t)row * NTOT + col] = f2bf(s);
                } else {
                    if (row - pb < cnt) {
                        int t = tids[row];
                        if (t >= 0 && t < BATCH)
                            atomicAdd(&Out[(size_t)t * HID + col], v * twt[row]);
                    }
                }
            }
        }
    }
}

// ---------- fallback (fused-convert GEMM, proven) if ws too small ----------
template <int KTOT, int NTOT, bool SILU>
__global__ __launch_bounds__(256, 2) void gemm_fused(
    const unsigned short* __restrict__ Abuf, const float* __restrict__ Wall,
    unsigned short* __restrict__ Hout, float* __restrict__ Out,
    const int* __restrict__ tids, const float* __restrict__ twt,
    const int* __restrict__ counts, const int* __restrict__ pbase) {
    __shared__ __align__(16) unsigned short sA[128][40];
    __shared__ __align__(16) unsigned short sB[128][40];
    int row0 = blockIdx.x * 128;
    if (row0 >= pbase[NEXP]) return;
    int e = 0;
    while (row0 >= pbase[e + 1]) e++;
    int n0 = blockIdx.y * 128;
    const float* Bw = Wall + (size_t)e * KTOT * NTOT;
    int tid = threadIdx.x;
    int lane = tid & 63, wid = tid >> 6;
    int wm = wid & 1, wn = wid >> 1;
    int quad = lane >> 4, l16 = lane & 15;
    floatx4 acc[4][4];
    #pragma unroll
    for (int i = 0; i < 4; i++)
        #pragma unroll
        for (int j = 0; j < 4; j++) acc[i][j] = (floatx4)0.f;
    for (int k0 = 0; k0 < KTOT; k0 += 32) {
        #pragma unroll
        for (int i = 0; i < 2; i++) {
            int q2 = tid + i * 256;
            int r = q2 >> 2, cc = (q2 & 3) * 8;
            uint4 v = *(const uint4*)(Abuf + (size_t)(row0 + r) * KTOT + k0 + cc);
            *(uint4*)(&sA[r][cc]) = v;
        }
        {
            int k = tid >> 3, n16 = (tid & 7) * 16;
            const float* bp = Bw + (size_t)(k0 + k) * NTOT + n0 + n16;
            #pragma unroll
            for (int j = 0; j < 4; j++) {
                float4 v = *(const float4*)(bp + j * 4);
                sB[n16 + j * 4 + 0][k] = f2bf(v.x);
                sB[n16 + j * 4 + 1][k] = f2bf(v.y);
                sB[n16 + j * 4 + 2][k] = f2bf(v.z);
                sB[n16 + j * 4 + 3][k] = f2bf(v.w);
            }
        }
        __syncthreads();
        short8 af[4], bfr[4];
        #pragma unroll
        for (int mi = 0; mi < 4; mi++)
            af[mi] = *(const short8*)(&sA[wm * 64 + mi * 16 + l16][quad * 8]);
        #pragma unroll
        for (int ni = 0; ni < 4; ni++)
            bfr[ni] = *(const short8*)(&sB[wn * 64 + ni * 16 + l16][quad * 8]);
        #pragma unroll
        for (int mi = 0; mi < 4; mi++)
            #pragma unroll
            for (int ni = 0; ni < 4; ni++)
                acc[mi][ni] = __builtin_amdgcn_mfma_f32_16x16x32_bf16(af[mi], bfr[ni], acc[mi][ni], 0, 0, 0);
        __syncthreads();
    }
    int cnt = counts[e], pb = pbase[e];
    #pragma unroll
    for (int mi = 0; mi < 4; mi++) {
        int rbase = row0 + wm * 64 + mi * 16 + quad * 4;
        #pragma unroll
        for (int ni = 0; ni < 4; ni++) {
            int col = n0 + wn * 64 + ni * 16 + l16;
            #pragma unroll
            for (int r = 0; r < 4; r++) {
                float v = acc[mi][ni][r];
                int row = rbase + r;
                if (SILU) {
                    float s = v / (1.f + __expf(-v));
                    Hout[(size_t)row * NTOT + col] = f2bf(s);
                } else {
                    if (row - pb < cnt) {
                        int t = tids[row];
                        if (t >= 0 && t < BATCH)
                            atomicAdd(&Out[(size_t)t * HID + col], v * twt[row]);
                    }
                }
            }
        }
    }
}

extern "C" void kernel_launch(void* const* d_in, const int* in_sizes, int n_in,
                              void* d_out, int out_size, void* d_ws, size_t ws_size,
                              hipStream_t stream) {
    const float* x = (const float*)d_in[0];
    const float* rw = (const float*)d_in[1];
    const float* w1 = (const float*)d_in[2];
    const float* w2 = (const float*)d_in[3];
    const int* idx32 = (const int*)d_in[4];
    float* out = (float*)d_out;

    char* ws = (char*)d_ws;
    int* counts = (int*)(ws + 0);
    int* cursor = (int*)(ws + 64);
    int* pbase  = (int*)(ws + 128);
    int* fmt    = (int*)(ws + 192);
    int* tids   = (int*)(ws + 4096);
    float* twt  = (float*)(ws + 4096 + MAXROWS * 4);

    size_t off = 65536;
    unsigned short* Apk  = (unsigned short*)(ws + off);  off += (size_t)MAXROWS * HID * 2;    // 10.5 MB
    unsigned short* Hact = (unsigned short*)(ws + off);  off += (size_t)MAXROWS * FFN * 2;    // 41.9 MB
    unsigned short* w1t  = (unsigned short*)(ws + off);  off += (size_t)NEXP * HID * FFN * 2; // 67.1 MB
    unsigned short* w2t  = (unsigned short*)(ws + off);  off += (size_t)NEXP * FFN * HID * 2; // 67.1 MB
    const bool big = ws_size >= off;   // constant per session -> graph-safe branch

    // zero meta + tids/twt + Apk in one shot (padding rows become true zeros)
    hipMemsetAsync(d_ws, 0, 65536 + (size_t)MAXROWS * HID * 2, stream);
    hipMemsetAsync(d_out, 0, (size_t)out_size * sizeof(float), stream);

    route_all<<<1, 1024, 0, stream>>>(idx32, fmt, counts, pbase, cursor);
    scatter_gather<<<BATCH, 128, 0, stream>>>(x, rw, idx32, fmt, cursor, tids, twt, Apk);

    if (big) {
        conv_transpose<<<dim3(FFN / 64, HID / 64, NEXP), 256, 0, stream>>>(w1, w1t, HID, FFN);
        conv_transpose<<<dim3(HID / 64, FFN / 64, NEXP), 256, 0, stream>>>(w2, w2t, FFN, HID);
        gemm_db<HID, FFN, true, 1, 0><<<dim3(MTILES, FFN / 128, 1), 256, 0, stream>>>(
            Apk, w1t, Hact, nullptr, tids, twt, counts, pbase);
        gemm_db<FFN, HID, false, 4, 1><<<dim3(MTILES, HID / 128, 4), 256, 0, stream>>>(
            Hact, w2t, nullptr, out, tids, twt, counts, pbase);
    } else {
        gemm_fused<HID, FFN, true><<<dim3(MTILES, FFN / 128), 256, 0, stream>>>(
            Apk, w1, Hact, nullptr, tids, twt, counts, pbase);
        gemm_fused<FFN, HID, false><<<dim3(MTILES, HID / 128), 256, 0, stream>>>(
            Hact, w2, nullptr, out, tids, twt, counts, pbase);
    }
}

// Round 3
// 535.419 us; speedup vs baseline: 1.1218x; 1.0864x over previous
//
#include <hip/hip_runtime.h>

#define BATCH 2048
#define HID 1024
#define FFN 4096
#define NEXP 8
#define MAXROWS 5120   // sum ceil(count_e/128)*128 <= 4096 + 8*127 -> round up
#define MTILES 40      // MAXROWS/128

typedef __attribute__((ext_vector_type(8))) short short8;
typedef __attribute__((ext_vector_type(4))) float floatx4;

// fp32 -> bf16 round-to-nearest-even
static __device__ inline unsigned short f2bf(float f) {
    unsigned int u = __float_as_uint(f);
    unsigned int r = (u + 0x7fffu + ((u >> 16) & 1u)) >> 16;
    return (unsigned short)r;
}

static __device__ inline int load_idx(const int* idx32, int flat, int is32) {
    return is32 ? idx32[flat] : idx32[2 * flat];  // int64 little-endian low word
}

// fused: detect int32/int64 layout, per-expert counts, padded prefix sum.
// Single block => __syncthreads gives the needed global ordering.
__global__ void route_all(const int* __restrict__ idx32, int* __restrict__ fmt,
                          int* __restrict__ counts, int* __restrict__ pbase,
                          int* __restrict__ cursor) {
    __shared__ int s_cnt[NEXP];
    __shared__ int s_fmt;
    int t = threadIdx.x;  // 1024 threads
    if (t < NEXP) s_cnt[t] = 0;
    if (t == 0) s_fmt = 0;
    __syncthreads();
    int bad = 0;
    for (int i = t; i < BATCH; i += 1024)       // odd words of first BATCH values
        if (idx32[2 * i + 1] != 0) bad = 1;     // in-bounds for both layouts
    if (bad) atomicOr(&s_fmt, 1);               // nonzero odd word -> plain int32
    __syncthreads();
    int is32 = s_fmt;
    for (int b = t; b < BATCH; b += 1024) {
        int e0 = load_idx(idx32, 2 * b, is32);
        int e1 = load_idx(idx32, 2 * b + 1, is32);
        atomicAdd(&s_cnt[e0], 1);
        if (e1 != e0) atomicAdd(&s_cnt[e1], 1);
    }
    __syncthreads();
    if (t == 0) {
        fmt[0] = is32;
        int acc = 0;
        for (int e = 0; e < NEXP; e++) {
            counts[e] = s_cnt[e];
            pbase[e] = acc;
            cursor[e] = acc;
            acc += ((s_cnt[e] + 127) >> 7) << 7;
        }
        pbase[NEXP] = acc;
    }
}

__global__ void scatter_gather(const float* __restrict__ x, const float* __restrict__ rw,
                               const int* __restrict__ idx32, const int* __restrict__ fmt,
                               int* __restrict__ cursor, int* __restrict__ tids,
                               float* __restrict__ twt, unsigned short* __restrict__ Apk) {
    __shared__ int s_slot[2];
    __shared__ int s_n;
    int b = blockIdx.x;
    if (threadIdx.x == 0) {
        int is32 = fmt[0];
        int e0 = load_idx(idx32, 2 * b, is32);
        int e1 = load_idx(idx32, 2 * b + 1, is32);
        float w0 = rw[2 * b], w1 = rw[2 * b + 1];
        int n, ee[2];
        float ww[2];
        if (e0 == e1) { n = 1; ee[0] = e0; ww[0] = w0 + w1; }
        else { n = 2; ee[0] = e0; ww[0] = w0; ee[1] = e1; ww[1] = w1; }
        for (int j = 0; j < n; j++) {
            int slot = atomicAdd(&cursor[ee[j]], 1);
            s_slot[j] = slot;
            tids[slot] = b;
            twt[slot] = ww[j];
        }
        s_n = n;
    }
    __syncthreads();
    int n = s_n;
    const float4* src = (const float4*)(x + (size_t)b * HID);
    for (int j = 0; j < n; j++) {
        unsigned short* dst = Apk + (size_t)s_slot[j] * HID;
        #pragma unroll
        for (int r = 0; r < 2; r++) {
            int i = threadIdx.x + r * 128;
            float4 v = src[i];
            union { unsigned short u[4]; uint2 q; } p;
            p.u[0] = f2bf(v.x); p.u[1] = f2bf(v.y);
            p.u[2] = f2bf(v.z); p.u[3] = f2bf(v.w);
            *(uint2*)(dst + i * 4) = p.q;
        }
    }
}

// convert fp32 W[E][K][N] -> bf16 Wt[E][N][K] (transpose via 64x64 LDS tile)
__global__ void conv_transpose(const float* __restrict__ W, unsigned short* __restrict__ Wt,
                               int K, int N) {
    __shared__ unsigned short sT[64][65];
    int e = blockIdx.z;
    int kt = blockIdx.y * 64, nt = blockIdx.x * 64;
    const float* src = W + ((size_t)e * K + kt) * N + nt;
    #pragma unroll
    for (int i = 0; i < 4; i++) {
        int t = threadIdx.x + i * 256;          // 0..1023, 64 rows x 16 float4
        int r = t >> 4, c4 = (t & 15) * 4;
        float4 v = *(const float4*)(src + (size_t)r * N + c4);
        sT[c4 + 0][r] = f2bf(v.x);
        sT[c4 + 1][r] = f2bf(v.y);
        sT[c4 + 2][r] = f2bf(v.z);
        sT[c4 + 3][r] = f2bf(v.w);
    }
    __syncthreads();
    #pragma unroll
    for (int i = 0; i < 2; i++) {
        int u = threadIdx.x + i * 256;          // 0..511, 64 rows x 8 uint4
        int n = u >> 3, k8 = (u & 7) * 8;
        union { unsigned short h[8]; uint4 q; } p;
        #pragma unroll
        for (int j = 0; j < 8; j++) p.h[j] = sT[n][k8 + j];
        *(uint4*)(Wt + ((size_t)e * N + nt + n) * K + kt + k8) = p.q;
    }
}

// Reg-staged double-buffered 128x128 tile, BK=32, register prefetch of next
// k-tile (compiler emits counted vmcnt waits -> loads stay in flight across
// the barrier), one barrier per iteration. NO XCD swizzle (A/B vs r2 showed
// the remap cost ~50us/gemm in this latency-bound, L3-resident regime).
// LDS slot-swizzle kept: 16B slot s of row r stored at s ^ ((r>>1)&3);
// fragment reads drop from 8-way to 2-way (free) bank aliasing
// (SQ_LDS_BANK_CONFLICT 4.19M -> 0 verified in r2).
// A: bf16 [rows][KTOT], Bt: bf16 [E][NTOT][KTOT].
template <int KTOT, int NTOT, bool SILU, int KSPLIT>
__global__ __launch_bounds__(256, 2) void gemm_db(
    const unsigned short* __restrict__ Abuf, const unsigned short* __restrict__ Bt,
    unsigned short* __restrict__ Hout, float* __restrict__ Out,
    const int* __restrict__ tids, const float* __restrict__ twt,
    const int* __restrict__ counts, const int* __restrict__ pbase) {
    __shared__ __align__(16) unsigned short sA[2][128 * 32];
    __shared__ __align__(16) unsigned short sB[2][128 * 32];

    int row0 = blockIdx.x * 128;
    if (row0 >= pbase[NEXP]) return;
    int e = 0;
    while (row0 >= pbase[e + 1]) e++;
    int n0 = blockIdx.y * 128;
    constexpr int KCH = KTOT / KSPLIT;
    constexpr int NK = KCH / 32;
    int kb = blockIdx.z * KCH;

    const unsigned short* Aw = Abuf + (size_t)row0 * KTOT + kb;
    const unsigned short* Bw = Bt + ((size_t)e * NTOT + n0) * KTOT + kb;

    int tid = threadIdx.x;
    int lane = tid & 63, wid = tid >> 6;
    int wm = wid & 1, wn = wid >> 1;
    int quad = lane >> 4, l16 = lane & 15;

    // staging: 512 16B-chunks per 128x32 tile; thread covers chunks tid and
    // tid+256 (rows r and r+64 -> same swizzle phase, dest +4096B).
    int r0 = tid >> 2, c8 = (tid & 3);
    const size_t aoff0 = (size_t)r0 * KTOT + c8 * 8;
    const size_t aoff1 = (size_t)(r0 + 64) * KTOT + c8 * 8;
    const int sl = c8 ^ ((r0 >> 1) & 3);
    const int ldso0 = r0 * 64 + sl * 16;       // bytes
    const int ldso1 = ldso0 + 4096;
    // fragment read slot (shorts): quad-th 16B of a row, swizzled by row phase
    const int sq = (quad ^ ((l16 >> 1) & 3)) * 8;

    floatx4 acc[4][4];
    #pragma unroll
    for (int i = 0; i < 4; i++)
        #pragma unroll
        for (int j = 0; j < 4; j++) acc[i][j] = (floatx4)0.f;

    uint4 va0 = *(const uint4*)(Aw + aoff0);
    uint4 va1 = *(const uint4*)(Aw + aoff1);
    uint4 vb0 = *(const uint4*)(Bw + aoff0);
    uint4 vb1 = *(const uint4*)(Bw + aoff1);
    *(uint4*)((char*)sA[0] + ldso0) = va0;
    *(uint4*)((char*)sA[0] + ldso1) = va1;
    *(uint4*)((char*)sB[0] + ldso0) = vb0;
    *(uint4*)((char*)sB[0] + ldso1) = vb1;
    __syncthreads();

    for (int k = 0;; k++) {
        int cur = k & 1;
        bool more = (k + 1 < NK);
        if (more) {
            const unsigned short* Ak = Aw + (k + 1) * 32;
            const unsigned short* Bk = Bw + (k + 1) * 32;
            va0 = *(const uint4*)(Ak + aoff0);
            va1 = *(const uint4*)(Ak + aoff1);
            vb0 = *(const uint4*)(Bk + aoff0);
            vb1 = *(const uint4*)(Bk + aoff1);
        }
        short8 af[4], bfv[4];
        #pragma unroll
        for (int mi = 0; mi < 4; mi++)
            af[mi] = *(const short8*)(sA[cur] + (wm * 64 + mi * 16 + l16) * 32 + sq);
        #pragma unroll
        for (int ni = 0; ni < 4; ni++)
            bfv[ni] = *(const short8*)(sB[cur] + (wn * 64 + ni * 16 + l16) * 32 + sq);
        #pragma unroll
        for (int mi = 0; mi < 4; mi++)
            #pragma unroll
            for (int ni = 0; ni < 4; ni++)
                acc[mi][ni] = __builtin_amdgcn_mfma_f32_16x16x32_bf16(af[mi], bfv[ni], acc[mi][ni], 0, 0, 0);
        if (!more) break;
        int nxt = cur ^ 1;
        *(uint4*)((char*)sA[nxt] + ldso0) = va0;
        *(uint4*)((char*)sA[nxt] + ldso1) = va1;
        *(uint4*)((char*)sB[nxt] + ldso0) = vb0;
        *(uint4*)((char*)sB[nxt] + ldso1) = vb1;
        __syncthreads();
    }

    int cnt = counts[e], pb = pbase[e];
    #pragma unroll
    for (int mi = 0; mi < 4; mi++) {
        int rbase = row0 + wm * 64 + mi * 16 + quad * 4;
        #pragma unroll
        for (int ni = 0; ni < 4; ni++) {
            int col = n0 + wn * 64 + ni * 16 + l16;
            #pragma unroll
            for (int r = 0; r < 4; r++) {
                float v = acc[mi][ni][r];
                int row = rbase + r;
                if (SILU) {
                    float s = v / (1.f + __expf(-v));
                    Hout[(size_t)row * NTOT + col] = f2bf(s);
                } else {
                    if (row - pb < cnt) {
                        int t = tids[row];
                        if (t >= 0 && t < BATCH)
                            atomicAdd(&Out[(size_t)t * HID + col], v * twt[row]);
                    }
                }
            }
        }
    }
}

// ---------- fallback (fused-convert GEMM, proven) if ws too small ----------
template <int KTOT, int NTOT, bool SILU>
__global__ __launch_bounds__(256, 2) void gemm_fused(
    const unsigned short* __restrict__ Abuf, const float* __restrict__ Wall,
    unsigned short* __restrict__ Hout, float* __restrict__ Out,
    const int* __restrict__ tids, const float* __restrict__ twt,
    const int* __restrict__ counts, const int* __restrict__ pbase) {
    __shared__ __align__(16) unsigned short sA[128][40];
    __shared__ __align__(16) unsigned short sB[128][40];
    int row0 = blockIdx.x * 128;
    if (row0 >= pbase[NEXP]) return;
    int e = 0;
    while (row0 >= pbase[e + 1]) e++;
    int n0 = blockIdx.y * 128;
    const float* Bw = Wall + (size_t)e * KTOT * NTOT;
    int tid = threadIdx.x;
    int lane = tid & 63, wid = tid >> 6;
    int wm = wid & 1, wn = wid >> 1;
    int quad = lane >> 4, l16 = lane & 15;
    floatx4 acc[4][4];
    #pragma unroll
    for (int i = 0; i < 4; i++)
        #pragma unroll
        for (int j = 0; j < 4; j++) acc[i][j] = (floatx4)0.f;
    for (int k0 = 0; k0 < KTOT; k0 += 32) {
        #pragma unroll
        for (int i = 0; i < 2; i++) {
            int q2 = tid + i * 256;
            int r = q2 >> 2, cc = (q2 & 3) * 8;
            uint4 v = *(const uint4*)(Abuf + (size_t)(row0 + r) * KTOT + k0 + cc);
            *(uint4*)(&sA[r][cc]) = v;
        }
        {
            int k = tid >> 3, n16 = (tid & 7) * 16;
            const float* bp = Bw + (size_t)(k0 + k) * NTOT + n0 + n16;
            #pragma unroll
            for (int j = 0; j < 4; j++) {
                float4 v = *(const float4*)(bp + j * 4);
                sB[n16 + j * 4 + 0][k] = f2bf(v.x);
                sB[n16 + j * 4 + 1][k] = f2bf(v.y);
                sB[n16 + j * 4 + 2][k] = f2bf(v.z);
                sB[n16 + j * 4 + 3][k] = f2bf(v.w);
            }
        }
        __syncthreads();
        short8 af[4], bfr[4];
        #pragma unroll
        for (int mi = 0; mi < 4; mi++)
            af[mi] = *(const short8*)(&sA[wm * 64 + mi * 16 + l16][quad * 8]);
        #pragma unroll
        for (int ni = 0; ni < 4; ni++)
            bfr[ni] = *(const short8*)(&sB[wn * 64 + ni * 16 + l16][quad * 8]);
        #pragma unroll
        for (int mi = 0; mi < 4; mi++)
            #pragma unroll
            for (int ni = 0; ni < 4; ni++)
                acc[mi][ni] = __builtin_amdgcn_mfma_f32_16x16x32_bf16(af[mi], bfr[ni], acc[mi][ni], 0, 0, 0);
        __syncthreads();
    }
    int cnt = counts[e], pb = pbase[e];
    #pragma unroll
    for (int mi = 0; mi < 4; mi++) {
        int rbase = row0 + wm * 64 + mi * 16 + quad * 4;
        #pragma unroll
        for (int ni = 0; ni < 4; ni++) {
            int col = n0 + wn * 64 + ni * 16 + l16;
            #pragma unroll
            for (int r = 0; r < 4; r++) {
                float v = acc[mi][ni][r];
                int row = rbase + r;
                if (SILU) {
                    float s = v / (1.f + __expf(-v));
                    Hout[(size_t)row * NTOT + col] = f2bf(s);
                } else {
                    if (row - pb < cnt) {
                        int t = tids[row];
                        if (t >= 0 && t < BATCH)
                            atomicAdd(&Out[(size_t)t * HID + col], v * twt[row]);
                    }
                }
            }
        }
    }
}

extern "C" void kernel_launch(void* const* d_in, const int* in_sizes, int n_in,
                              void* d_out, int out_size, void* d_ws, size_t ws_size,
                              hipStream_t stream) {
    const float* x = (const float*)d_in[0];
    const float* rw = (const float*)d_in[1];
    const float* w1 = (const float*)d_in[2];
    const float* w2 = (const float*)d_in[3];
    const int* idx32 = (const int*)d_in[4];
    float* out = (float*)d_out;

    char* ws = (char*)d_ws;
    int* counts = (int*)(ws + 0);
    int* cursor = (int*)(ws + 64);
    int* pbase  = (int*)(ws + 128);
    int* fmt    = (int*)(ws + 192);
    int* tids   = (int*)(ws + 4096);
    float* twt  = (float*)(ws + 4096 + MAXROWS * 4);

    size_t off = 65536;
    unsigned short* Apk  = (unsigned short*)(ws + off);  off += (size_t)MAXROWS * HID * 2;    // 10.5 MB
    unsigned short* Hact = (unsigned short*)(ws + off);  off += (size_t)MAXROWS * FFN * 2;    // 41.9 MB
    unsigned short* w1t  = (unsigned short*)(ws + off);  off += (size_t)NEXP * HID * FFN * 2; // 67.1 MB
    unsigned short* w2t  = (unsigned short*)(ws + off);  off += (size_t)NEXP * FFN * HID * 2; // 67.1 MB
    const bool big = ws_size >= off;   // constant per session -> graph-safe branch

    // zero meta + tids/twt + Apk in one shot (padding rows become true zeros)
    hipMemsetAsync(d_ws, 0, 65536 + (size_t)MAXROWS * HID * 2, stream);
    hipMemsetAsync(d_out, 0, (size_t)out_size * sizeof(float), stream);

    route_all<<<1, 1024, 0, stream>>>(idx32, fmt, counts, pbase, cursor);
    scatter_gather<<<BATCH, 128, 0, stream>>>(x, rw, idx32, fmt, cursor, tids, twt, Apk);

    if (big) {
        conv_transpose<<<dim3(FFN / 64, HID / 64, NEXP), 256, 0, stream>>>(w1, w1t, HID, FFN);
        conv_transpose<<<dim3(HID / 64, FFN / 64, NEXP), 256, 0, stream>>>(w2, w2t, FFN, HID);
        gemm_db<HID, FFN, true, 1><<<dim3(MTILES, FFN / 128, 1), 256, 0, stream>>>(
            Apk, w1t, Hact, nullptr, tids, twt, counts, pbase);
        gemm_db<FFN, HID, false, 4><<<dim3(MTILES, HID / 128, 4), 256, 0, stream>>>(
            Hact, w2t, nullptr, out, tids, twt, counts, pbase);
    } else {
        gemm_fused<HID, FFN, true><<<dim3(MTILES, FFN / 128), 256, 0, stream>>>(
            Apk, w1, Hact, nullptr, tids, twt, counts, pbase);
        gemm_fused<FFN, HID, false><<<dim3(MTILES, HID / 128), 256, 0, stream>>>(
            Hact, w2, nullptr, out, tids, twt, counts, pbase);
    }
}